// Round 10
// baseline (81.047 us; speedup 1.0000x reference)
//
#include <hip/hip_runtime.h>
#include <hip/hip_bf16.h>
#include <stdint.h>

// Fused single-head causal attention: q=x@Wq, k=x@Wk, v=x@Wv,
// out = softmax(causal(q k^T/8)) @ v.  B=256, T=256, C=768, H=64.
// One block per batch (256 blocks = 1 per CU), 512 threads (8 waves).
// Phase 1 (R10): BK=64 K-steps (12 windows, HALF the barriers of R6).
//   x+Wt double-buffered in LDS with 128B rows + XOR swizzle ^((row&7)<<4)
//   (guide G4 pattern); Wt PRE-swizzled by wt_prep so linear staging copies
//   land swizzled. 2-deep register prefetch, lgkmcnt-only barriers.
//   K/V LDS regions OVERLAY the dead staging buffers after phase 1.
// Phase 2: swapped QK^T, balanced causal pairing (w,15-w), no max-sub,
//   deferred normalization, operand-swapped PV -> float4 out stores.

typedef __attribute__((ext_vector_type(8))) short short8;
typedef __attribute__((ext_vector_type(4))) short short4v;
typedef __attribute__((ext_vector_type(4))) float f32x4;

#define MFMA16(a, b, c) __builtin_amdgcn_mfma_f32_16x16x32_bf16(a, b, c, 0, 0, 0)

// barrier that does NOT drain vmcnt: LDS visibility only.
#define BAR() do { \
  asm volatile("s_waitcnt lgkmcnt(0)" ::: "memory"); \
  __builtin_amdgcn_s_barrier(); \
} while (0)

static __device__ __forceinline__ unsigned short f2bf(float f) {
  union { float f; uint32_t u; } v; v.f = f;
  return (unsigned short)((v.u + 0x7FFFu + ((v.u >> 16) & 1u)) >> 16);  // RNE
}

// -------- prep: W -> WtT [12 it][192 rows][64 cols] bf16, PRE-SWIZZLED -----
// element (it,row,c) = W_{row/64}[(it*64+c)*64 + (row&63)]; Wq scaled 1/8.
// stored at short index  it*12288 + row*64 + (c ^ ((row&7)<<3))   (= byte
// (c*2)^((row&7)<<4) within the 128B row) so a LINEAR global->LDS copy lands
// in the swizzled layout the b-frag reads expect.
__global__ void wt_prep(const float* __restrict__ Wq, const float* __restrict__ Wk,
                        const float* __restrict__ Wv, unsigned short* __restrict__ WtT) {
  int idx = blockIdx.x * 256 + threadIdx.x;  // 36*64*64 = 147456
  if (idx >= 147456) return;
  int co = idx & 63;
  int c = (idx >> 6) & 63;
  int itm = idx >> 12;          // 0..35
  int it = itm / 3;
  int m = itm - it * 3;
  const float* W = (m == 0) ? Wq : (m == 1 ? Wk : Wv);
  float v = W[(it * 64 + c) * 64 + co];
  if (m == 0) v *= 0.125f;  // fold 1/sqrt(H) into Wq
  int row = m * 64 + co;
  WtT[it * 12288 + row * 64 + (c ^ ((row & 7) << 3))] = f2bf(v);
}

// LDS layout (bytes), 131072 total:
//  [0,32768)        xs buf0 [256 rows][128B bf16] swz ^((row&7)<<4)
//  [32768,65536)    xs buf1
//  [65536,90112)    ws buf0 [192 rows][128B bf16] swz (pre-swizzled source)
//  [90112,114688)   ws buf1
//  phase-2 overlays (all staging dead after the loop):
//   Q [0,65536)      [256 rows][256B] swz ^((row&15)<<4)
//   K [65536,98304)  [256 keys][128B] swz ^((key&7)<<4)
//   V [98304,131072) [64 h][512B]     swz ^((h&7)<<4)
//   P: wave w uses [w*8192,+8192) of the Q region
#define XS0 0
#define XS1 32768
#define WS0 65536
#define WS1 90112
#define KOFF 65536
#define VOFF 98304

__global__ __launch_bounds__(512, 2) void fused_head(
    const float* __restrict__ x, const unsigned short* __restrict__ WtT,
    float* __restrict__ out) {
  __shared__ char smem[131072];
  const int tid = threadIdx.x;
  const int w = tid >> 6;
  const int lane = tid & 63;
  const int l15 = lane & 15, g = lane >> 4;
  const int b = blockIdx.x;
  const float* xB = x + (size_t)b * 256 * 768;

  char* xs0 = smem + XS0;
  char* xs1 = smem + XS1;
  char* ws0 = smem + WS0;
  char* ws1 = smem + WS1;

  // ---------------- phase 1: QKV projection, BK=64, 12 windows -------------
  f32x4 acc[2][12];
  #pragma unroll
  for (int rt = 0; rt < 2; ++rt)
    #pragma unroll
    for (int ct = 0; ct < 12; ++ct) acc[rt][ct] = f32x4{0.f, 0.f, 0.f, 0.f};

  const int sc = tid & 15;       // 8B-chunk within 128B row
  const int sr0 = tid >> 4;      // row base 0..31 (8 slabs of 32 rows)
  const bool stv = (tid < 384);  // Wt staging: 384 threads x 64B = 24576B

  float4 xA[8], xPB[8];
  short8 wA[4], wPB[4];

  auto loadX = [&](float4* xr, int it) {
    const float* src = xB + (size_t)sr0 * 768 + it * 64 + sc * 4;
    #pragma unroll
    for (int p = 0; p < 8; ++p)
      xr[p] = *reinterpret_cast<const float4*>(src + (size_t)p * 32 * 768);
  };
  auto loadW = [&](short8* wr, int it) {
    if (stv) {
      const char* src = (const char*)WtT + (size_t)it * 24576 + tid * 16;
      #pragma unroll
      for (int k = 0; k < 4; ++k)
        wr[k] = *reinterpret_cast<const short8*>(src + k * 6144);
    }
  };
  auto storeX = [&](char* xsb, const float4* xr) {
    #pragma unroll
    for (int p = 0; p < 8; ++p) {
      int row = p * 32 + sr0;
      short4v v;
      v[0] = (short)f2bf(xr[p].x); v[1] = (short)f2bf(xr[p].y);
      v[2] = (short)f2bf(xr[p].z); v[3] = (short)f2bf(xr[p].w);
      *reinterpret_cast<short4v*>(xsb + row * 128 + ((sc * 8) ^ ((row & 7) << 4))) = v;
    }
  };
  auto storeW = [&](char* wsb, const short8* wr) {
    if (stv) {
      #pragma unroll
      for (int k = 0; k < 4; ++k)
        *reinterpret_cast<short8*>(wsb + tid * 16 + k * 6144) = wr[k];
    }
  };
  auto compute = [&](const char* xsb, const char* wsb) {
    #pragma unroll
    for (int kh = 0; kh < 2; ++kh) {
      short8 a0, a1;
      {
        int r0 = w * 32 + l15;
        int r1 = r0 + 16;
        a0 = *reinterpret_cast<const short8*>(
            xsb + r0 * 128 + ((kh * 64 + g * 16) ^ ((r0 & 7) << 4)));
        a1 = *reinterpret_cast<const short8*>(
            xsb + r1 * 128 + ((kh * 64 + g * 16) ^ ((r1 & 7) << 4)));
      }
      #pragma unroll
      for (int ct = 0; ct < 12; ++ct) {
        int row = ct * 16 + l15;
        short8 bb = *reinterpret_cast<const short8*>(
            wsb + row * 128 + ((kh * 64 + g * 16) ^ ((row & 7) << 4)));
        acc[0][ct] = MFMA16(a0, bb, acc[0][ct]);
        acc[1][ct] = MFMA16(a1, bb, acc[1][ct]);
      }
    }
  };

  // prologue: tile0 -> bufs0 ; tile1 -> reg set B
  loadX(xA, 0); loadW(wA, 0);
  storeX(xs0, xA); storeW(ws0, wA);
  loadX(xPB, 1); loadW(wPB, 1);
  BAR();

  #pragma unroll 1
  for (int jo = 0; jo < 6; ++jo) {
    // even window n=2jo: compute tile 2jo from bufs0
    {
      if (jo < 5) { loadX(xA, 2 * jo + 2); loadW(wA, 2 * jo + 2); }
      compute(xs0, ws0);
      storeX(xs1, xPB); storeW(ws1, wPB);  // tile 2jo+1 -> bufs1
      BAR();
    }
    // odd window n=2jo+1: compute tile 2jo+1 from bufs1
    {
      if (jo < 5) { loadX(xPB, 2 * jo + 3); loadW(wPB, 2 * jo + 3); }
      compute(xs1, ws1);
      if (jo < 5) { storeX(xs0, xA); storeW(ws0, wA); }  // tile 2jo+2 -> bufs0
      BAR();
    }
  }

  // ---------------- epilogue: accs -> LDS (K, Vt, Q) ----------------
  char* Kl = smem + KOFF;
  char* Vl = smem + VOFF;
  char* Ql = smem;
  #pragma unroll
  for (int rt = 0; rt < 2; ++rt) {
    #pragma unroll
    for (int ct = 0; ct < 4; ++ct) {
      #pragma unroll
      for (int r = 0; r < 4; ++r) {
        int key = w * 32 + rt * 16 + g * 4 + r;
        int h = ct * 16 + l15;
        *reinterpret_cast<unsigned short*>(
            Kl + key * 128 + ((h * 2) ^ ((key & 7) << 4))) = f2bf(acc[rt][4 + ct][r]);
        *reinterpret_cast<unsigned short*>(
            Ql + key * 256 + ((h * 2) ^ ((key & 15) << 4))) = f2bf(acc[rt][ct][r]);
      }
      int h = ct * 16 + l15;
      int t0 = w * 32 + rt * 16 + g * 4;
      short4v pv;
      pv[0] = (short)f2bf(acc[rt][8 + ct][0]); pv[1] = (short)f2bf(acc[rt][8 + ct][1]);
      pv[2] = (short)f2bf(acc[rt][8 + ct][2]); pv[3] = (short)f2bf(acc[rt][8 + ct][3]);
      *reinterpret_cast<short4v*>(Vl + h * 512 + ((t0 * 2) ^ ((h & 7) << 4))) = pv;
    }
  }
  BAR();  // K/V/Q visible to all waves

  // read Q fragments for this wave's two (balanced) q-tiles: w and 15-w
  short8 qf[2][2];
  #pragma unroll
  for (int rt = 0; rt < 2; ++rt) {
    const int qrow0 = (rt == 0) ? w * 16 : (15 - w) * 16;
    #pragma unroll
    for (int c = 0; c < 2; ++c) {
      int row = qrow0 + l15;
      qf[rt][c] = *reinterpret_cast<const short8*>(
          Ql + row * 256 + ((c * 64 + g * 16) ^ ((row & 15) << 4)));
    }
  }
  BAR();  // ALL qf reads done before ANY P write (P overlays the Q region)

  // ---------------- phase 2: causal attention ----------------
  char* Pw = smem + w * 8192;  // [16 rows][512B], swz ^((l15&7)<<4)

  #pragma unroll
  for (int rt = 0; rt < 2; ++rt) {
    const int tile_idx = (rt == 0) ? w : 15 - w;
    const int trow0 = tile_idx * 16;
    const int ntile = tile_idx + 1;  // causal: key tiles 0..ntile-1
    const int pswz = (l15 & 7) << 4;

    // S^T = K Q^T : D row = key-local (g*4+r), col = q-local (l15)
    f32x4 s[16];
    #pragma unroll
    for (int t = 0; t < 16; ++t) {
      if (t < ntile) {
        int key = t * 16 + l15;
        int kswz = (key & 7) << 4;
        short8 k0 = *reinterpret_cast<const short8*>(Kl + key * 128 + ((g * 16) ^ kswz));
        short8 k1 = *reinterpret_cast<const short8*>(Kl + key * 128 + ((64 + g * 16) ^ kswz));
        f32x4 a = f32x4{0.f, 0.f, 0.f, 0.f};
        a = MFMA16(k0, qf[rt][0], a);
        a = MFMA16(k1, qf[rt][1], a);
        s[t] = a;
      }
    }

    // exp (no max-sub: scores bounded), mask diagonal, write P unnormalized
    float sum = 0.f;
    #pragma unroll
    for (int t = 0; t < 16; ++t) {
      if (t < ntile) {
        const bool diag = (t == ntile - 1);
        short4v pk;
        #pragma unroll
        for (int r = 0; r < 4; ++r) {
          float p = __expf(s[t][r]);
          if (diag && (g * 4 + r > l15)) p = 0.f;  // causal mask
          sum += p;
          pk[r] = (short)f2bf(p);
        }
        *reinterpret_cast<short4v*>(Pw + l15 * 512 + ((t * 32 + g * 8) ^ pswz)) = pk;
      }
    }
    if (ntile & 1) {  // zero-pad tile ntile so the last 32-key PV chunk is clean
      *reinterpret_cast<short4v*>(Pw + l15 * 512 + ((ntile * 32 + g * 8) ^ pswz)) =
          short4v{0, 0, 0, 0};
    }
    sum += __shfl_xor(sum, 16);
    sum += __shfl_xor(sum, 32);
    const float inv = 1.0f / sum;  // denominator for q-row (trow0 + l15)

    // O^T = (P V)^T via operand swap: D row = h-local (g*4+r), col = q (l15)
    const int nkc = (ntile + 1) >> 1;
    f32x4 o[4];
    #pragma unroll
    for (int i = 0; i < 4; ++i) o[i] = f32x4{0.f, 0.f, 0.f, 0.f};
    #pragma unroll
    for (int kc = 0; kc < 8; ++kc) {
      if (kc < nkc) {
        short8 pa = *reinterpret_cast<const short8*>(
            Pw + l15 * 512 + ((kc * 64 + g * 16) ^ pswz));
        #pragma unroll
        for (int ht = 0; ht < 4; ++ht) {
          int h = ht * 16 + l15;
          short8 bv = *reinterpret_cast<const short8*>(
              Vl + h * 512 + ((kc * 64 + g * 16) ^ ((h & 7) << 4)));
          o[ht] = MFMA16(bv, pa, o[ht]);  // swapped: A=V^T rows, B=P rows
        }
      }
    }

    // store out fp32: lane holds O[q=trow0+l15][h = ht*16 + g*4 .. +4]
    {
      float* dst = out + ((size_t)b * 256 + trow0 + l15) * 64 + g * 4;
      #pragma unroll
      for (int ht = 0; ht < 4; ++ht) {
        float4 ov;
        ov.x = o[ht][0] * inv; ov.y = o[ht][1] * inv;
        ov.z = o[ht][2] * inv; ov.w = o[ht][3] * inv;
        *reinterpret_cast<float4*>(dst + ht * 16) = ov;
      }
    }
  }
}

// ---------------------------------------------------------------- launch
extern "C" void kernel_launch(void* const* d_in, const int* in_sizes, int n_in,
                              void* d_out, int out_size, void* d_ws, size_t ws_size,
                              hipStream_t stream) {
  const float* x  = (const float*)d_in[0];
  const float* Wq = (const float*)d_in[1];
  const float* Wk = (const float*)d_in[2];
  const float* Wv = (const float*)d_in[3];
  unsigned short* WtT = (unsigned short*)d_ws;  // 12*24576 = 294912 B
  float* out = (float*)d_out;

  hipLaunchKernelGGL(wt_prep, dim3(576), dim3(256), 0, stream, Wq, Wk, Wv, WtT);
  hipLaunchKernelGGL(fused_head, dim3(256), dim3(512), 0, stream, x, WtT, out);
}

// Round 11
// 49.237 us; speedup vs baseline: 1.6461x; 1.6461x over previous
//
#include <hip/hip_runtime.h>
#include <hip/hip_bf16.h>
#include <stdint.h>

// Fused single-head causal attention: q=x@Wq, k=x@Wk, v=x@Wv,
// out = softmax(causal(q k^T/8)) @ v.  B=256, T=256, C=768, H=64.
// One block per batch (256 blocks = 1 per CU), 512 threads (8 waves).
// Phase 1 (R11 = R6 + 3-deep prefetch): x+Wt double-buffered LDS; THREE
//   named register sets (A/B/C) rotate over the 2 LDS buffers so tile n+3's
//   global loads are issued in window n (~2.5 windows of latency cover,
//   ~64-80KB in flight per CU). lgkmcnt-only barriers.
// Phase 2: swapped QK^T, balanced causal pairing (w,15-w), no max-sub,
//   deferred normalization, operand-swapped PV -> float4 out stores.

typedef __attribute__((ext_vector_type(8))) short short8;
typedef __attribute__((ext_vector_type(4))) short short4v;
typedef __attribute__((ext_vector_type(4))) float f32x4;

#define MFMA16(a, b, c) __builtin_amdgcn_mfma_f32_16x16x32_bf16(a, b, c, 0, 0, 0)

// barrier that does NOT drain vmcnt: LDS visibility only.
#define BAR() do { \
  asm volatile("s_waitcnt lgkmcnt(0)" ::: "memory"); \
  __builtin_amdgcn_s_barrier(); \
} while (0)

static __device__ __forceinline__ unsigned short f2bf(float f) {
  union { float f; uint32_t u; } v; v.f = f;
  return (unsigned short)((v.u + 0x7FFFu + ((v.u >> 16) & 1u)) >> 16);  // RNE
}

// ---------------- prep: W -> WtT tiled [24 it][192 r][40 shorts] (pad 8) ----
// element (it,r,c) = W_{r/64}[(it*32+c)*64 + (r&63)] ; Wq pre-scaled 1/8.
__global__ void wt_prep(const float* __restrict__ Wq, const float* __restrict__ Wk,
                        const float* __restrict__ Wv, unsigned short* __restrict__ WtT) {
  int idx = blockIdx.x * 256 + threadIdx.x;  // 24*3*32*64 = 147456
  if (idx >= 147456) return;
  int co = idx & 63;
  int c = (idx >> 6) & 31;
  int itm = idx >> 11;          // 0..71
  int it = itm / 3;
  int m = itm - it * 3;
  const float* W = (m == 0) ? Wq : (m == 1 ? Wk : Wv);
  float v = W[(it * 32 + c) * 64 + co];
  if (m == 0) v *= 0.125f;  // fold 1/sqrt(H) into Wq
  WtT[it * 7680 + (m * 64 + co) * 40 + c] = f2bf(v);
}

// LDS layout (bytes):
//  [0,20480)       xs buf0 [256 rows][40 shorts]
//  [20480,40960)   xs buf1
//  [40960,56320)   ws buf0 [192 rows][40 shorts]
//  [56320,71680)   ws buf1
//  [71680,104448)  K  [256 keys][64 h]  stride 128B, swz ^((key&7)<<4)
//  [104448,137216) Vt [64 h][256 t]     stride 512B, swz ^((h&7)<<4)
//  overlays (phase 2): Q [256 rows][256B] swz ^((row&15)<<4) at [0,65536)
//                      P: wave w uses [w*8192,+8192) = [16 rows][512B]
//                         swz ^((l15&7)<<4)
#define XS0 0
#define XS1 20480
#define WS0 40960
#define WS1 56320
#define KOFF 71680
#define VOFF 104448

__global__ __launch_bounds__(512, 2) void fused_head(
    const float* __restrict__ x, const unsigned short* __restrict__ WtT,
    float* __restrict__ out) {
  __shared__ char smem[137216];
  const int tid = threadIdx.x;
  const int w = tid >> 6;
  const int lane = tid & 63;
  const int l15 = lane & 15, g = lane >> 4;
  const int b = blockIdx.x;
  const float* xB = x + (size_t)b * 256 * 768;

  char* xsb_[2] = { smem + XS0, smem + XS1 };
  char* wsb_[2] = { smem + WS0, smem + WS1 };

  // ---------------- phase 1: QKV projection ----------------
  f32x4 acc[2][12];
  #pragma unroll
  for (int rt = 0; rt < 2; ++rt)
    #pragma unroll
    for (int ct = 0; ct < 12; ++ct) acc[rt][ct] = f32x4{0.f, 0.f, 0.f, 0.f};

  const int sxr = tid >> 3;   // x staging: row within 64-row band
  const int sxc = tid & 7;    // 16B chunk
  const bool stv = (tid < 480);

  float4 xS[3][4];            // named 3-deep x register sets
  short8 wS[3][2];            // named 3-deep W register sets

  auto loadX = [&](float4* xr, int kk) {
    #pragma unroll
    for (int p = 0; p < 4; ++p)
      xr[p] = *reinterpret_cast<const float4*>(
          xB + (size_t)(p * 64 + sxr) * 768 + kk + sxc * 4);
  };
  auto loadW = [&](short8* wr, int it) {
    if (stv) {
      const short8* s = reinterpret_cast<const short8*>(WtT + (size_t)it * 7680 + tid * 16);
      wr[0] = s[0]; wr[1] = s[1];
    }
  };
  auto storeX = [&](char* xsb, const float4* xr) {
    #pragma unroll
    for (int p = 0; p < 4; ++p) {
      short4v v;
      v[0] = (short)f2bf(xr[p].x); v[1] = (short)f2bf(xr[p].y);
      v[2] = (short)f2bf(xr[p].z); v[3] = (short)f2bf(xr[p].w);
      *reinterpret_cast<short4v*>(xsb + (p * 64 + sxr) * 80 + sxc * 8) = v;
    }
  };
  auto storeW = [&](char* wsb, const short8* wr) {
    if (stv) {
      *reinterpret_cast<short8*>(wsb + tid * 32) = wr[0];
      *reinterpret_cast<short8*>(wsb + tid * 32 + 16) = wr[1];
    }
  };
  auto compute = [&](const char* xsb, const char* wsb) {
    short8 a0 = *reinterpret_cast<const short8*>(xsb + (w * 32 + l15) * 80 + g * 16);
    short8 a1 = *reinterpret_cast<const short8*>(xsb + (w * 32 + 16 + l15) * 80 + g * 16);
    #pragma unroll
    for (int ct = 0; ct < 12; ++ct) {
      short8 bb = *reinterpret_cast<const short8*>(wsb + (ct * 16 + l15) * 80 + g * 16);
      acc[0][ct] = MFMA16(a0, bb, acc[0][ct]);
      acc[1][ct] = MFMA16(a1, bb, acc[1][ct]);
    }
  };

  // prologue: tile0 -> set0 -> LDS bufs0 ; tile1 -> set1 ; tile2 -> set2
  loadX(xS[0], 0);  loadW(wS[0], 0);
  storeX(xsb_[0], xS[0]); storeW(wsb_[0], wS[0]);
  loadX(xS[1], 32); loadW(wS[1], 1);
  loadX(xS[2], 64); loadW(wS[2], 2);
  BAR();

  // window n: refill set(n%3) <- tile n+3 ; compute buf(n%2) (tile n) ;
  //           store set((n+1)%3) -> buf((n+1)%2) ; BAR.
  // 24 windows = 4 groups x 6 (LCM of 2 and 3) -> all indices static.
  #pragma unroll 1
  for (int j = 0; j < 4; ++j) {
    const int n0 = 6 * j;
    #pragma unroll
    for (int p = 0; p < 6; ++p) {
      const int n = n0 + p;
      if (n < 21) { loadX(xS[p % 3], (n + 3) * 32); loadW(wS[p % 3], n + 3); }
      compute(xsb_[p & 1], wsb_[p & 1]);
      if (n < 23) {
        storeX(xsb_[(p + 1) & 1], xS[(p + 1) % 3]);
        storeW(wsb_[(p + 1) & 1], wS[(p + 1) % 3]);
      }
      BAR();
    }
  }

  // ---------------- epilogue: accs -> LDS (K, Vt, Q) ----------------
  char* Kl = smem + KOFF;
  char* Vl = smem + VOFF;
  char* Ql = smem;
  #pragma unroll
  for (int rt = 0; rt < 2; ++rt) {
    #pragma unroll
    for (int ct = 0; ct < 4; ++ct) {
      #pragma unroll
      for (int r = 0; r < 4; ++r) {
        int key = w * 32 + rt * 16 + g * 4 + r;
        int h = ct * 16 + l15;
        *reinterpret_cast<unsigned short*>(
            Kl + key * 128 + ((h * 2) ^ ((key & 7) << 4))) = f2bf(acc[rt][4 + ct][r]);
        *reinterpret_cast<unsigned short*>(
            Ql + key * 256 + ((h * 2) ^ ((key & 15) << 4))) = f2bf(acc[rt][ct][r]);
      }
      int h = ct * 16 + l15;
      int t0 = w * 32 + rt * 16 + g * 4;
      short4v pv;
      pv[0] = (short)f2bf(acc[rt][8 + ct][0]); pv[1] = (short)f2bf(acc[rt][8 + ct][1]);
      pv[2] = (short)f2bf(acc[rt][8 + ct][2]); pv[3] = (short)f2bf(acc[rt][8 + ct][3]);
      *reinterpret_cast<short4v*>(Vl + h * 512 + ((t0 * 2) ^ ((h & 7) << 4))) = pv;
    }
  }
  BAR();  // K/V/Q visible to all waves

  // read Q fragments for this wave's two (balanced) q-tiles: w and 15-w
  short8 qf[2][2];
  #pragma unroll
  for (int rt = 0; rt < 2; ++rt) {
    const int qrow0 = (rt == 0) ? w * 16 : (15 - w) * 16;
    #pragma unroll
    for (int c = 0; c < 2; ++c) {
      int row = qrow0 + l15;
      qf[rt][c] = *reinterpret_cast<const short8*>(
          Ql + row * 256 + ((c * 64 + g * 16) ^ ((row & 15) << 4)));
    }
  }
  BAR();  // ALL qf reads done before ANY P write (P overlays the Q region)

  // ---------------- phase 2: causal attention ----------------
  char* Pw = smem + w * 8192;  // [16 rows][512B], swz ^((l15&7)<<4)

  #pragma unroll
  for (int rt = 0; rt < 2; ++rt) {
    const int tile_idx = (rt == 0) ? w : 15 - w;
    const int trow0 = tile_idx * 16;
    const int ntile = tile_idx + 1;  // causal: key tiles 0..ntile-1
    const int pswz = (l15 & 7) << 4;

    // S^T = K Q^T : D row = key-local (g*4+r), col = q-local (l15)
    f32x4 s[16];
    #pragma unroll
    for (int t = 0; t < 16; ++t) {
      if (t < ntile) {
        int key = t * 16 + l15;
        int kswz = (key & 7) << 4;
        short8 k0 = *reinterpret_cast<const short8*>(Kl + key * 128 + ((g * 16) ^ kswz));
        short8 k1 = *reinterpret_cast<const short8*>(Kl + key * 128 + ((64 + g * 16) ^ kswz));
        f32x4 a = f32x4{0.f, 0.f, 0.f, 0.f};
        a = MFMA16(k0, qf[rt][0], a);
        a = MFMA16(k1, qf[rt][1], a);
        s[t] = a;
      }
    }

    // exp (no max-sub: scores bounded), mask diagonal, write P unnormalized
    // (4 consecutive keys/lane -> b64), accumulate sum.
    float sum = 0.f;
    #pragma unroll
    for (int t = 0; t < 16; ++t) {
      if (t < ntile) {
        const bool diag = (t == ntile - 1);
        short4v pk;
        #pragma unroll
        for (int r = 0; r < 4; ++r) {
          float p = __expf(s[t][r]);
          if (diag && (g * 4 + r > l15)) p = 0.f;  // causal mask
          sum += p;
          pk[r] = (short)f2bf(p);
        }
        *reinterpret_cast<short4v*>(Pw + l15 * 512 + ((t * 32 + g * 8) ^ pswz)) = pk;
      }
    }
    if (ntile & 1) {  // zero-pad tile ntile so the last 32-key PV chunk is clean
      *reinterpret_cast<short4v*>(Pw + l15 * 512 + ((ntile * 32 + g * 8) ^ pswz)) =
          short4v{0, 0, 0, 0};
    }
    sum += __shfl_xor(sum, 16);
    sum += __shfl_xor(sum, 32);
    const float inv = 1.0f / sum;  // denominator for q-row (trow0 + l15)

    // O^T = (P V)^T via operand swap: D row = h-local (g*4+r), col = q (l15)
    const int nkc = (ntile + 1) >> 1;
    f32x4 o[4];
    #pragma unroll
    for (int i = 0; i < 4; ++i) o[i] = f32x4{0.f, 0.f, 0.f, 0.f};
    #pragma unroll
    for (int kc = 0; kc < 8; ++kc) {
      if (kc < nkc) {
        short8 pa = *reinterpret_cast<const short8*>(
            Pw + l15 * 512 + ((kc * 64 + g * 16) ^ pswz));
        #pragma unroll
        for (int ht = 0; ht < 4; ++ht) {
          int h = ht * 16 + l15;
          short8 bv = *reinterpret_cast<const short8*>(
              Vl + h * 512 + ((kc * 64 + g * 16) ^ ((h & 7) << 4)));
          o[ht] = MFMA16(bv, pa, o[ht]);  // swapped: A=V^T rows, B=P rows
        }
      }
    }

    // store out fp32: lane holds O[q=trow0+l15][h = ht*16 + g*4 .. +4]
    {
      float* dst = out + ((size_t)b * 256 + trow0 + l15) * 64 + g * 4;
      #pragma unroll
      for (int ht = 0; ht < 4; ++ht) {
        float4 ov;
        ov.x = o[ht][0] * inv; ov.y = o[ht][1] * inv;
        ov.z = o[ht][2] * inv; ov.w = o[ht][3] * inv;
        *reinterpret_cast<float4*>(dst + ht * 16) = ov;
      }
    }
  }
}

// ---------------------------------------------------------------- launch
extern "C" void kernel_launch(void* const* d_in, const int* in_sizes, int n_in,
                              void* d_out, int out_size, void* d_ws, size_t ws_size,
                              hipStream_t stream) {
  const float* x  = (const float*)d_in[0];
  const float* Wq = (const float*)d_in[1];
  const float* Wk = (const float*)d_in[2];
  const float* Wv = (const float*)d_in[3];
  unsigned short* WtT = (unsigned short*)d_ws;  // 24*7680*2 = 368640 B
  float* out = (float*)d_out;

  hipLaunchKernelGGL(wt_prep, dim3(576), dim3(256), 0, stream, Wq, Wk, Wv, WtT);
  hipLaunchKernelGGL(fused_head, dim3(256), dim3(512), 0, stream, x, WtT, out);
}